// Round 1
// baseline (163.306 us; speedup 1.0000x reference)
//
#include <hip/hip_runtime.h>

// SLAYER 2-layer SNN, MI355X. Key transform: alpha_psp (temporal LTI, pointwise
// in space) commutes with conv2d_t (spatial, pointwise in time), so both convs
// run on BINARY spike trains -> bit-packed uint64 per pixel, conv = bit-test+fma.
// One fused kernel: 16x16 output tile / 256-thread block, 2 barriers total.

#define HH   192
#define WW   192
#define NIMG 4
#define TT   64
#define TILE 16
#define E1   18   // TILE + 2  (s1 / conv1-output domain, radius 1 for conv2)
#define E3   22   // TILE + 6  (raw-input domain, +2 more for conv1)
#define NT   256

// float64 coefficient math folded at compile time, then cast to f32 (matches
// reference's np.exp/np.e in f64 -> jnp f32 cast).
#define E_D 2.718281828459045
static constexpr float D1  = (float)0.36787944117144233;   // exp(-1/tau1), tau1=1
static constexpr float CP1 = (float)(E_D);                 // e*TS/tau*TS, tau=1
static constexpr float DR1 = (float)0.36787944117144233;   // exp(-1/tauRef1)
static constexpr float CR1 = (float)(-30.0 * E_D);         // -theta*e/tauRef
static constexpr float D2  = (float)0.6065306597126334;    // exp(-1/tau2), tau2=2
static constexpr float CP2 = (float)(E_D * 0.5);           // e/2
static constexpr float DR2 = (float)0.6065306597126334;    // exp(-1/tauRef2)
static constexpr float CR2 = (float)(-50.0 * E_D * 0.5);   // -25e
static constexpr float TH1 = 30.0f;
static constexpr float TH2 = 50.0f;

__global__ __launch_bounds__(NT)
void snn_fused(const float* __restrict__ in, const float* __restrict__ w1g,
               const float* __restrict__ w2g, float* __restrict__ out) {
    __shared__ unsigned inLo[E3 * E3];
    __shared__ unsigned inHi[E3 * E3];
    __shared__ unsigned s1Lo[E1 * E1];
    __shared__ unsigned s1Hi[E1 * E1];

    const int n   = blockIdx.z;
    const int y0  = blockIdx.y * TILE;
    const int x0  = blockIdx.x * TILE;
    const int tid = threadIdx.x;

    // Weights: uniform loads -> scalar regs (hoisted once).
    float w1[25];
#pragma unroll
    for (int k = 0; k < 25; k++) w1[k] = w1g[k];
    float w2[9];
#pragma unroll
    for (int k = 0; k < 9; k++) w2[k] = w2g[k];

    // ---------------- Phase 0: pack raw input spikes (E3 halo) into bits ----
    for (int task = tid; task < E3 * E3; task += NT) {
        const int ey = task / E3, ex = task - ey * E3;
        const int gy = y0 - 3 + ey, gx = x0 - 3 + ex;
        unsigned lo = 0u, hi = 0u;
        if (gy >= 0 && gy < HH && gx >= 0 && gx < WW) {
            const float4* p = reinterpret_cast<const float4*>(
                in + (((size_t)n * HH + gy) * WW + gx) * TT);
#pragma unroll
            for (int c = 0; c < 16; c++) {
                float4 v = p[c];
                unsigned b = (v.x != 0.f ? 1u : 0u) | (v.y != 0.f ? 2u : 0u)
                           | (v.z != 0.f ? 4u : 0u) | (v.w != 0.f ? 8u : 0u);
                if (c < 8) lo |= b << (4 * c);
                else       hi |= b << (4 * (c - 8));
            }
        }
        inLo[task] = lo;
        inHi[task] = hi;
    }
    __syncthreads();

    // ---------------- Phase A: conv1(bits) -> psp1 -> lif1 -> s1 bits -------
    for (int task = tid; task < E1 * E1; task += NT) {
        const int ly = task / E1, lx = task - ly * E1;
        const int gy = y0 - 1 + ly, gx = x0 - 1 + lx;
        unsigned slo = 0u, shi = 0u;
        if (gy >= 0 && gy < HH && gx >= 0 && gx < WW) {
            float u1 = 0.f, v1 = 0.f, ur = 0.f, vr = 0.f;
            unsigned tap[25];
#pragma unroll
            for (int i = 0; i < 5; i++)
#pragma unroll
                for (int j = 0; j < 5; j++)
                    tap[i * 5 + j] = inLo[(ly + i) * E3 + (lx + j)];
#pragma unroll 2
            for (int t = 0; t < 32; t++) {
                float a0 = 0.f, a1 = 0.f, a2 = 0.f, a3 = 0.f;
#pragma unroll
                for (int k = 0; k < 25; k++) {
                    float b = (float)((tap[k] >> t) & 1u);
                    if ((k & 3) == 0) a0 += w1[k] * b;
                    else if ((k & 3) == 1) a1 += w1[k] * b;
                    else if ((k & 3) == 2) a2 += w1[k] * b;
                    else a3 += w1[k] * b;
                }
                float c = (a0 + a1) + (a2 + a3);
                v1 = D1 * (v1 + u1);            // psp1: v_new (x_t weight 0)
                float p = CP1 * v1;
                u1 = D1 * u1 + c;
                vr = DR1 * (vr + ur);           // lif1 refractory state
                float m = p + CR1 * vr;
                bool sp = (m >= TH1);
                ur = DR1 * ur + (sp ? 1.f : 0.f);
                slo |= sp ? (1u << t) : 0u;
            }
#pragma unroll
            for (int i = 0; i < 5; i++)
#pragma unroll
                for (int j = 0; j < 5; j++)
                    tap[i * 5 + j] = inHi[(ly + i) * E3 + (lx + j)];
#pragma unroll 2
            for (int t = 0; t < 32; t++) {
                float a0 = 0.f, a1 = 0.f, a2 = 0.f, a3 = 0.f;
#pragma unroll
                for (int k = 0; k < 25; k++) {
                    float b = (float)((tap[k] >> t) & 1u);
                    if ((k & 3) == 0) a0 += w1[k] * b;
                    else if ((k & 3) == 1) a1 += w1[k] * b;
                    else if ((k & 3) == 2) a2 += w1[k] * b;
                    else a3 += w1[k] * b;
                }
                float c = (a0 + a1) + (a2 + a3);
                v1 = D1 * (v1 + u1);
                float p = CP1 * v1;
                u1 = D1 * u1 + c;
                vr = DR1 * (vr + ur);
                float m = p + CR1 * vr;
                bool sp = (m >= TH1);
                ur = DR1 * ur + (sp ? 1.f : 0.f);
                shi |= sp ? (1u << t) : 0u;
            }
        }
        // out-of-image pixels must contribute ZERO to conv2 (jax zero-pad)
        s1Lo[task] = slo;
        s1Hi[task] = shi;
    }
    __syncthreads();

    // ---------------- Phase B: conv2(s1 bits) -> psp2 -> lif2 -> s2 bits ----
    // exactly one task per thread (TILE*TILE == NT)
    {
        const int oy = tid / TILE, ox = tid - oy * TILE;
        const int gy = y0 + oy, gx = x0 + ox;
        unsigned olo = 0u, ohi = 0u;
        float u2 = 0.f, v2 = 0.f, ur2 = 0.f, vr2 = 0.f;
        unsigned tap[9];
#pragma unroll
        for (int i = 0; i < 3; i++)
#pragma unroll
            for (int j = 0; j < 3; j++)
                tap[i * 3 + j] = s1Lo[(oy + i) * E1 + (ox + j)];
#pragma unroll 4
        for (int t = 0; t < 32; t++) {
            float a0 = 0.f, a1 = 0.f, a2 = 0.f;
#pragma unroll
            for (int k = 0; k < 9; k++) {
                float b = (float)((tap[k] >> t) & 1u);
                if (k % 3 == 0) a0 += w2[k] * b;
                else if (k % 3 == 1) a1 += w2[k] * b;
                else a2 += w2[k] * b;
            }
            float c = a0 + a1 + a2;
            v2 = D2 * (v2 + u2);
            float p = CP2 * v2;
            u2 = D2 * u2 + c;
            vr2 = DR2 * (vr2 + ur2);
            float m = p + CR2 * vr2;
            bool sp = (m >= TH2);
            ur2 = DR2 * ur2 + (sp ? 1.f : 0.f);
            olo |= sp ? (1u << t) : 0u;
        }
#pragma unroll
        for (int i = 0; i < 3; i++)
#pragma unroll
            for (int j = 0; j < 3; j++)
                tap[i * 3 + j] = s1Hi[(oy + i) * E1 + (ox + j)];
#pragma unroll 4
        for (int t = 0; t < 32; t++) {
            float a0 = 0.f, a1 = 0.f, a2 = 0.f;
#pragma unroll
            for (int k = 0; k < 9; k++) {
                float b = (float)((tap[k] >> t) & 1u);
                if (k % 3 == 0) a0 += w2[k] * b;
                else if (k % 3 == 1) a1 += w2[k] * b;
                else a2 += w2[k] * b;
            }
            float c = a0 + a1 + a2;
            v2 = D2 * (v2 + u2);
            float p = CP2 * v2;
            u2 = D2 * u2 + c;
            vr2 = DR2 * (vr2 + ur2);
            float m = p + CR2 * vr2;
            bool sp = (m >= TH2);
            ur2 = DR2 * ur2 + (sp ? 1.f : 0.f);
            ohi |= sp ? (1u << t) : 0u;
        }

        // -------- Phase C: unpack s2 bits -> float spikes, coalesced-ish ----
        float* op = out + (((size_t)n * HH + gy) * WW + gx) * TT;
#pragma unroll
        for (int c = 0; c < 16; c++) {
            const unsigned word = (c < 8) ? olo : ohi;
            const int sh = (4 * c) & 31;
            float4 v;
            v.x = (float)((word >> (sh + 0)) & 1u);
            v.y = (float)((word >> (sh + 1)) & 1u);
            v.z = (float)((word >> (sh + 2)) & 1u);
            v.w = (float)((word >> (sh + 3)) & 1u);
            reinterpret_cast<float4*>(op)[c] = v;
        }
    }
}

extern "C" void kernel_launch(void* const* d_in, const int* in_sizes, int n_in,
                              void* d_out, int out_size, void* d_ws, size_t ws_size,
                              hipStream_t stream) {
    const float* in  = (const float*)d_in[0];   // (4,1,192,192,64) f32 spikes
    const float* w1  = (const float*)d_in[1];   // (1,1,5,5)
    const float* w2  = (const float*)d_in[2];   // (1,1,3,3)
    float* out = (float*)d_out;                 // (4,1,192,192,64) f32 spikes

    dim3 grid(WW / TILE, HH / TILE, NIMG);      // 12 x 12 x 4 = 576 blocks
    snn_fused<<<grid, NT, 0, stream>>>(in, w1, w2, out);
}